// Round 4
// baseline (568.442 us; speedup 1.0000x reference)
//
#include <hip/hip_runtime.h>
#include <stdint.h>

// Problem constants
#define B_   4
#define NQ_  2048
#define SK_  2048
#define H_   16
#define HS_  1024   // HSIZE = OSIZE = ISIZE
#define D_   64

typedef __attribute__((ext_vector_type(8))) short bf16x8;          // MFMA A/B frag (4 VGPR)
typedef __attribute__((ext_vector_type(4))) float f32x4;           // MFMA C/D frag
typedef __attribute__((ext_vector_type(8))) unsigned short u16x8;  // 8 bf16 = 16B
typedef __attribute__((ext_vector_type(4))) int i32x4;             // 4 int32 = 16B

#define DEVI __device__ __forceinline__

DEVI float bf2f(unsigned short u) {
  union { unsigned int i; float f; } x; x.i = ((unsigned int)u) << 16; return x.f;
}
DEVI unsigned short f2bf(float f) {  // round-to-nearest-even
  union { float f; unsigned int i; } x; x.f = f;
  unsigned int r = x.i + 0x7fffu + ((x.i >> 16) & 1u);
  return (unsigned short)(r >> 16);
}
DEVI u16x8 cvt8(f32x4 lo, f32x4 hi) {  // 8 fp32 -> 8 bf16 (RNE)
  u16x8 p;
#pragma unroll
  for (int c = 0; c < 4; c++) p[c] = f2bf(lo[c]);
#pragma unroll
  for (int c = 0; c < 4; c++) p[c + 4] = f2bf(hi[c]);
  return p;
}

// ---------------------------------------------------------------------------
// C[M][N] = A[M][K] @ W[N][K]^T, bf16 MFMA with fp32 accumulate.
// ABF16: A is bf16 (internal buffer) else fp32 (harness input, cvt on stage).
// CF32:  C is fp32 (final output)   else bf16 (internal buffer).
// W is always fp32 (harness weights). 128x128 tile, BK=32, 4 waves.
// LDS rows padded 32->40 shorts: frag ds_read_b128 2-way aliased (free, m136).
// ---------------------------------------------------------------------------
template <bool ABF16, bool CF32>
__global__ __launch_bounds__(256)
void gemm_bt(const void* __restrict__ Ap, const float* __restrict__ W,
             void* __restrict__ Cp, int M, int N, int K) {
  __shared__ unsigned short As[128 * 40];
  __shared__ unsigned short Bs[128 * 40];
  const int t = threadIdx.x;
  const int w = t >> 6, l = t & 63;
  const int lm = l & 15, lg = l >> 4;
  const int bm = blockIdx.x * 128, bn = blockIdx.y * 128;
  const int wm = (w >> 1) * 64, wn = (w & 1) * 64;

  // staging coords: thread t covers (row = t>>2 [+64], cols (t&3)*8 .. +7)
  const int sr = t >> 2, sc = (t & 3) * 8;
  const float* Af = (const float*)Ap;
  const unsigned short* Ab = (const unsigned short*)Ap;
  const size_t ao0 = (size_t)(bm + sr) * K + sc;
  const size_t ao1 = (size_t)(bm + sr + 64) * K + sc;
  const size_t wo0 = (size_t)(bn + sr) * K + sc;
  const size_t wo1 = (size_t)(bn + sr + 64) * K + sc;

  auto loadA = [&](size_t off) -> u16x8 {
    if constexpr (ABF16) {
      return *(const u16x8*)(Ab + off);
    } else {
      f32x4 lo = *(const f32x4*)(Af + off);
      f32x4 hi = *(const f32x4*)(Af + off + 4);
      return cvt8(lo, hi);
    }
  };
  auto loadW = [&](size_t off) -> u16x8 {
    f32x4 lo = *(const f32x4*)(W + off);
    f32x4 hi = *(const f32x4*)(W + off + 4);
    return cvt8(lo, hi);
  };

  // prefetch k-slice 0
  u16x8 pa0 = loadA(ao0), pa1 = loadA(ao1);
  u16x8 pb0 = loadW(wo0), pb1 = loadW(wo1);

  f32x4 acc[4][4] = {};

  for (int k0 = 0; k0 < K; k0 += 32) {
    *(u16x8*)&As[sr * 40 + sc]        = pa0;
    *(u16x8*)&As[(sr + 64) * 40 + sc] = pa1;
    *(u16x8*)&Bs[sr * 40 + sc]        = pb0;
    *(u16x8*)&Bs[(sr + 64) * 40 + sc] = pb1;
    __syncthreads();
    if (k0 + 32 < K) {  // overlap next global loads with MFMA phase
      pa0 = loadA(ao0 + k0 + 32);
      pa1 = loadA(ao1 + k0 + 32);
      pb0 = loadW(wo0 + k0 + 32);
      pb1 = loadW(wo1 + k0 + 32);
    }
    bf16x8 aF[4], bF[4];
#pragma unroll
    for (int i = 0; i < 4; i++)
      aF[i] = *(const bf16x8*)&As[(wm + i * 16 + lm) * 40 + lg * 8];
#pragma unroll
    for (int i = 0; i < 4; i++)
      bF[i] = *(const bf16x8*)&Bs[(wn + i * 16 + lm) * 40 + lg * 8];
#pragma unroll
    for (int i = 0; i < 4; i++)
#pragma unroll
      for (int j = 0; j < 4; j++)
        acc[i][j] = __builtin_amdgcn_mfma_f32_16x16x32_bf16(aF[i], bF[j], acc[i][j], 0, 0, 0);
    __syncthreads();
  }
  // epilogue: C/D layout col=lm (n), row=lg*4+r (m)
#pragma unroll
  for (int i = 0; i < 4; i++)
#pragma unroll
    for (int j = 0; j < 4; j++) {
      const int row = bm + wm + i * 16 + lg * 4;
      const int col = bn + wn + j * 16 + lm;
#pragma unroll
      for (int r = 0; r < 4; r++) {
        if constexpr (CF32) {
          ((float*)Cp)[(size_t)(row + r) * N + col] = acc[i][j][r];
        } else {
          ((unsigned short*)Cp)[(size_t)(row + r) * N + col] = f2bf(acc[i][j][r]);
        }
      }
    }
}

// ---------------------------------------------------------------------------
// SparseNormer attention, one (b, h, 128-q tile) per block, 256 threads.
// Q/K/V are bf16 internal buffers; mask is int32 (numpy bool -> int per the
// harness "integer -> const int*" rule). S^T = K.Q^T (C-layout regs = 4
// consecutive sk at fixed q: mask for a frag is one aligned int4 load, P
// writes are packed b64), then O^T = V^T.P^T. Numerator/denominator
// accumulate across 32 K-tiles of 64 keys; one divide at the end
// (ratio of sums -- no online max needed for relu^2/sum).
// ---------------------------------------------------------------------------
__global__ __launch_bounds__(256)
void attn_sn(const unsigned short* __restrict__ Qb,
             const unsigned short* __restrict__ Kb,
             const unsigned short* __restrict__ Vb,
             const int* __restrict__ mask,
             const float* __restrict__ snb,
             unsigned short* __restrict__ Ob) {
  __shared__ unsigned short Ks[64 * 72];    // [key][d], pad 64->72
  __shared__ unsigned short Vt[64 * 72];    // [d][sk] transposed, pad->72
  __shared__ unsigned short Pq[128 * 72];   // [q][sk] bf16 P; reused as [q][d] O-stage
  __shared__ float denomS[128];

  const int h = blockIdx.x, qt = blockIdx.y, b = blockIdx.z;
  const int t = threadIdx.x, w = t >> 6, l = t & 63;
  const int lm = l & 15, lg = l >> 4;
  const int q0 = qt * 128;
  const int wk = (w >> 1) * 32;   // wave's sk rows (S^T) == d rows (PV)
  const int wn = (w & 1) * 64;    // wave's q cols (both phases)
  const float bias = snb[0];

  // resident Q fragments: B-operand of S^T (n=q, k=d)
  bf16x8 bQ[4][2];
#pragma unroll
  for (int ni = 0; ni < 4; ni++)
#pragma unroll
    for (int kf = 0; kf < 2; kf++) {
      const int qq = q0 + wn + ni * 16 + lm;
      bQ[ni][kf] = *(const bf16x8*)&Qb[(size_t)(b * NQ_ + qq) * HS_ + h * D_ + kf * 32 + lg * 8];
    }

  // K staging coords: thread t loads rows (t>>3, t>>3+32), cols (t&7)*8..+7
  const int kr = t >> 3, kc = (t & 7) * 8;
  const unsigned short* Kg = Kb + (size_t)(b * SK_) * HS_ + h * D_ + kc;
  // V transpose coords: rows 2*va, 2*va+1, cols vc..vc+7
  const int va = t & 31;
  const int vc = (t >> 5) * 8;
  const unsigned short* Vg = Vb + (size_t)(b * SK_) * HS_ + h * D_ + vc;
  const int* mbase = mask + (size_t)b * NQ_ * SK_;

  f32x4 oacc[2][4] = {};
  float dpart[4] = {0.f, 0.f, 0.f, 0.f};

  for (int kt = 0; kt < SK_ / 64; kt++) {
    const int kk0 = kt * 64;
    // --- stage K tile (64 keys x 64 d)
    u16x8 k0v = *(const u16x8*)(Kg + (size_t)(kk0 + kr) * HS_);
    u16x8 k1v = *(const u16x8*)(Kg + (size_t)(kk0 + 32 + kr) * HS_);
    *(u16x8*)&Ks[kr * 72 + kc]        = k0v;
    *(u16x8*)&Ks[(kr + 32) * 72 + kc] = k1v;
    // --- stage V transposed: packed u32-pair writes
    u16x8 v0 = *(const u16x8*)(Vg + (size_t)(kk0 + 2 * va) * HS_);
    u16x8 v1 = *(const u16x8*)(Vg + (size_t)(kk0 + 2 * va + 1) * HS_);
#pragma unroll
    for (int c = 0; c < 8; c++) {
      unsigned int pv = (unsigned int)v0[c] | ((unsigned int)v1[c] << 16);
      *(unsigned int*)&Vt[(vc + c) * 72 + 2 * va] = pv;
    }
    __syncthreads();

    // --- S^T = K . Q^T  (A = K rows)
    bf16x8 aK[2][2];
#pragma unroll
    for (int mi = 0; mi < 2; mi++)
#pragma unroll
      for (int kf = 0; kf < 2; kf++)
        aK[mi][kf] = *(const bf16x8*)&Ks[(wk + mi * 16 + lm) * 72 + kf * 32 + lg * 8];
    f32x4 sf[2][4] = {};
#pragma unroll
    for (int mi = 0; mi < 2; mi++)
#pragma unroll
      for (int ni = 0; ni < 4; ni++) {
        sf[mi][ni] = __builtin_amdgcn_mfma_f32_16x16x32_bf16(aK[mi][0], bQ[ni][0], sf[mi][ni], 0, 0, 0);
        sf[mi][ni] = __builtin_amdgcn_mfma_f32_16x16x32_bf16(aK[mi][1], bQ[ni][1], sf[mi][ni], 0, 0, 0);
      }

    // --- mask (int32) + relu^2, denom partial (on bf16-rounded values,
    //     matching the numerator's P exactly), pack P -> LDS (b64 per frag)
#pragma unroll
    for (int ni = 0; ni < 4; ni++) {
      const int qq = q0 + wn + ni * 16 + lm;
      const int* mrow = mbase + (size_t)qq * SK_ + kk0 + wk + lg * 4;
#pragma unroll
      for (int mi = 0; mi < 2; mi++) {
        const i32x4 mw = *(const i32x4*)(mrow + mi * 16);
        const f32x4 sv = sf[mi][ni];
        unsigned short pr[4]; float dsum = 0.f;
#pragma unroll
        for (int r = 0; r < 4; r++) {
          float x = sv[r] * 0.125f + bias;   // scores/sqrt(64) + sn_bias
          x = fmaxf(x, 0.f);
          x = mw[r] ? 0.f : x;               // mask==True -> -1e32 -> relu 0
          x = x * x;
          const unsigned short xb = f2bf(x);
          pr[r] = xb;
          dsum += bf2f(xb);
        }
        dpart[ni] += dsum;
        const unsigned long long pk =
            (unsigned long long)((unsigned int)pr[0] | ((unsigned int)pr[1] << 16)) |
            ((unsigned long long)((unsigned int)pr[2] | ((unsigned int)pr[3] << 16)) << 32);
        *(unsigned long long*)&Pq[(wn + ni * 16 + lm) * 72 + wk + mi * 16 + lg * 4] = pk;
      }
    }
    __syncthreads();

    // --- O^T += V^T . P^T
#pragma unroll
    for (int k2 = 0; k2 < 2; k2++) {
      bf16x8 aV[2], bP[4];
#pragma unroll
      for (int mi = 0; mi < 2; mi++)
        aV[mi] = *(const bf16x8*)&Vt[(wk + mi * 16 + lm) * 72 + k2 * 32 + lg * 8];
#pragma unroll
      for (int ni = 0; ni < 4; ni++)
        bP[ni] = *(const bf16x8*)&Pq[(wn + ni * 16 + lm) * 72 + k2 * 32 + lg * 8];
#pragma unroll
      for (int mi = 0; mi < 2; mi++)
#pragma unroll
        for (int ni = 0; ni < 4; ni++)
          oacc[mi][ni] = __builtin_amdgcn_mfma_f32_16x16x32_bf16(aV[mi], bP[ni], oacc[mi][ni], 0, 0, 0);
    }
    __syncthreads();
  }

  // --- denominator: reduce 4 lane-groups (shfl) then combine 2 sk-wave-halves
#pragma unroll
  for (int ni = 0; ni < 4; ni++) {
    float v = dpart[ni];
    v += __shfl_xor(v, 16, 64);
    v += __shfl_xor(v, 32, 64);
    dpart[ni] = v;
  }
  if (((w >> 1) == 0) && (lg == 0)) {
#pragma unroll
    for (int ni = 0; ni < 4; ni++) denomS[wn + ni * 16 + lm] = dpart[ni];
  }
  __syncthreads();
  if (((w >> 1) == 1) && (lg == 0)) {
#pragma unroll
    for (int ni = 0; ni < 4; ni++) denomS[wn + ni * 16 + lm] += dpart[ni];
  }
  __syncthreads();

  // --- normalize, stage O[q][d] into Pq (packed b64), then coalesced store
#pragma unroll
  for (int ni = 0; ni < 4; ni++) {
    const int ql = wn + ni * 16 + lm;
    const float inv = 1.0f / (denomS[ql] + 1e-32f);
#pragma unroll
    for (int mi = 0; mi < 2; mi++) {
      const int d0 = wk + mi * 16 + lg * 4;
      const f32x4 ov = oacc[mi][ni];
      const unsigned long long pk =
          (unsigned long long)((unsigned int)f2bf(ov[0] * inv) | ((unsigned int)f2bf(ov[1] * inv) << 16)) |
          ((unsigned long long)((unsigned int)f2bf(ov[2] * inv) | ((unsigned int)f2bf(ov[3] * inv) << 16)) << 32);
      *(unsigned long long*)&Pq[ql * 72 + d0] = pk;
    }
  }
  __syncthreads();
  const int qf = t >> 1;
  const int dg = (t & 1) * 32;
  unsigned short* orow = Ob + (size_t)(b * NQ_ + q0 + qf) * HS_ + h * D_ + dg;
#pragma unroll
  for (int j = 0; j < 4; j++) {
    u16x8 vv = *(const u16x8*)&Pq[qf * 72 + dg + j * 8];
    *(u16x8*)(orow + j * 8) = vv;
  }
}

// ---------------------------------------------------------------------------
extern "C" void kernel_launch(void* const* d_in, const int* in_sizes, int n_in,
                              void* d_out, int out_size, void* d_ws, size_t ws_size,
                              hipStream_t stream) {
  (void)in_sizes; (void)n_in; (void)out_size;
  const float* iQ  = (const float*)d_in[0];
  const float* iK  = (const float*)d_in[1];
  const float* iV  = (const float*)d_in[2];
  const int*   msk = (const int*)d_in[3];   // numpy bool -> int32 per harness
  const float* Wq  = (const float*)d_in[4];
  const float* Wk  = (const float*)d_in[5];
  const float* Wv  = (const float*)d_in[6];
  const float* Wo  = (const float*)d_in[7];
  const float* snb = (const float*)d_in[8];
  float* out = (float*)d_out;

  const size_t TOK = (size_t)B_ * NQ_ * HS_;  // 8.39M elems; bf16 buf = 16.78 MB
  unsigned short *Qb, *Kb, *Vb, *Ob;
  if (ws_size >= 4 * TOK * sizeof(unsigned short)) {
    Qb = (unsigned short*)d_ws;
    Kb = Qb + TOK;
    Vb = Qb + 2 * TOK;
    Ob = Qb + 3 * TOK;
  } else {
    // fallback: stage Q in d_out (fp32 buffer, 33.5 MB >= 16.78 MB; dead
    // until the final GEMM overwrites it after attention completed)
    Qb = (unsigned short*)d_out;
    Kb = (unsigned short*)d_ws;
    Vb = Kb + TOK;
    Ob = Kb + 2 * TOK;
  }

  dim3 gg(64, 8, 1), bb(256, 1, 1);
  const int M = B_ * NQ_, N = HS_, K = HS_;
  hipLaunchKernelGGL((gemm_bt<false, false>), gg, bb, 0, stream, (const void*)iQ, Wq, (void*)Qb, M, N, K);
  hipLaunchKernelGGL((gemm_bt<false, false>), gg, bb, 0, stream, (const void*)iK, Wk, (void*)Kb, M, N, K);
  hipLaunchKernelGGL((gemm_bt<false, false>), gg, bb, 0, stream, (const void*)iV, Wv, (void*)Vb, M, N, K);
  // h fastest-varying: 16 consecutive blocks share one mask/Q tile -> L2 reuse
  hipLaunchKernelGGL(attn_sn, dim3(H_, NQ_ / 128, B_), bb, 0, stream,
                     Qb, Kb, Vb, msk, snb, Ob);
  hipLaunchKernelGGL((gemm_bt<true, true>), gg, bb, 0, stream, (const void*)Ob, Wo, (void*)out, M, N, K);
}

// Round 5
// 498.519 us; speedup vs baseline: 1.1403x; 1.1403x over previous
//
#include <hip/hip_runtime.h>
#include <stdint.h>

// Problem constants
#define B_   4
#define NQ_  2048
#define SK_  2048
#define H_   16
#define HS_  1024   // HSIZE = OSIZE = ISIZE
#define D_   64

typedef __attribute__((ext_vector_type(8))) short bf16x8;          // MFMA A/B frag (4 VGPR)
typedef __attribute__((ext_vector_type(4))) float f32x4;           // MFMA C/D frag
typedef __attribute__((ext_vector_type(8))) unsigned short u16x8;  // 8 bf16 = 16B
typedef __attribute__((ext_vector_type(4))) int i32x4;             // 4 int32 = 16B

#define DEVI __device__ __forceinline__

// fp32 -> bf16, round-half-up (1 v_add; ties differ from RNE by 1 ulp, negligible)
DEVI unsigned short f2bf_hu(float f) {
  union { float f; unsigned int i; } x; x.f = f;
  return (unsigned short)((x.i + 0x8000u) >> 16);
}
// two fp32 -> packed bf16x2 in ONE v_perm (plus 2 v_add): result = bf16(b)<<16 | bf16(a)
DEVI unsigned int pack2(float a, float b) {
  union { float f; unsigned int i; } x, y; x.f = a; y.f = b;
  return __builtin_amdgcn_perm(y.i + 0x8000u, x.i + 0x8000u, 0x07060302u);
}
DEVI u16x8 cvt8(f32x4 lo, f32x4 hi) {  // 8 fp32 -> 8 bf16: 8 add + 4 perm
  union { u16x8 s; unsigned int w[4]; } r;
  r.w[0] = pack2(lo[0], lo[1]);
  r.w[1] = pack2(lo[2], lo[3]);
  r.w[2] = pack2(hi[0], hi[1]);
  r.w[3] = pack2(hi[2], hi[3]);
  return r.s;
}

// ---------------------------------------------------------------------------
// C[M][N] = A[M][K] @ W[N][K]^T, bf16 MFMA with fp32 accumulate.
// ABF16: A is bf16 (internal buffer) else fp32 (harness input, cvt on stage).
// CF32:  C is fp32 (final output)   else bf16 (internal buffer).
// W is always fp32. 128x128 tile, BK=32, 4 waves, register-prefetch pipeline.
// LDS rows padded 32->40 shorts: frag ds_read_b128 2-way aliased (free, m136).
// ---------------------------------------------------------------------------
template <bool ABF16, bool CF32>
__global__ __launch_bounds__(256)
void gemm_bt(const void* __restrict__ Ap, const float* __restrict__ W,
             void* __restrict__ Cp, int M, int N, int K) {
  __shared__ unsigned short As[128 * 40];
  __shared__ unsigned short Bs[128 * 40];
  const int t = threadIdx.x;
  const int w = t >> 6, l = t & 63;
  const int lm = l & 15, lg = l >> 4;
  const int bm = blockIdx.x * 128, bn = blockIdx.y * 128;
  const int wm = (w >> 1) * 64, wn = (w & 1) * 64;

  // staging coords: thread t covers (row = t>>2 [+64], cols (t&3)*8 .. +7)
  const int sr = t >> 2, sc = (t & 3) * 8;
  const float* Af = (const float*)Ap;
  const unsigned short* Ab = (const unsigned short*)Ap;
  const size_t ao0 = (size_t)(bm + sr) * K + sc;
  const size_t ao1 = (size_t)(bm + sr + 64) * K + sc;
  const size_t wo0 = (size_t)(bn + sr) * K + sc;
  const size_t wo1 = (size_t)(bn + sr + 64) * K + sc;

  auto loadA = [&](size_t off) -> u16x8 {
    if constexpr (ABF16) {
      return *(const u16x8*)(Ab + off);
    } else {
      f32x4 lo = *(const f32x4*)(Af + off);
      f32x4 hi = *(const f32x4*)(Af + off + 4);
      return cvt8(lo, hi);
    }
  };
  auto loadW = [&](size_t off) -> u16x8 {
    f32x4 lo = *(const f32x4*)(W + off);
    f32x4 hi = *(const f32x4*)(W + off + 4);
    return cvt8(lo, hi);
  };

  // prefetch k-slice 0
  u16x8 pa0 = loadA(ao0), pa1 = loadA(ao1);
  u16x8 pb0 = loadW(wo0), pb1 = loadW(wo1);

  f32x4 acc[4][4] = {};

  for (int k0 = 0; k0 < K; k0 += 32) {
    *(u16x8*)&As[sr * 40 + sc]        = pa0;
    *(u16x8*)&As[(sr + 64) * 40 + sc] = pa1;
    *(u16x8*)&Bs[sr * 40 + sc]        = pb0;
    *(u16x8*)&Bs[(sr + 64) * 40 + sc] = pb1;
    __syncthreads();
    if (k0 + 32 < K) {  // overlap next global loads + cvt with MFMA phase
      pa0 = loadA(ao0 + k0 + 32);
      pa1 = loadA(ao1 + k0 + 32);
      pb0 = loadW(wo0 + k0 + 32);
      pb1 = loadW(wo1 + k0 + 32);
    }
    bf16x8 aF[4], bF[4];
#pragma unroll
    for (int i = 0; i < 4; i++)
      aF[i] = *(const bf16x8*)&As[(wm + i * 16 + lm) * 40 + lg * 8];
#pragma unroll
    for (int i = 0; i < 4; i++)
      bF[i] = *(const bf16x8*)&Bs[(wn + i * 16 + lm) * 40 + lg * 8];
#pragma unroll
    for (int i = 0; i < 4; i++)
#pragma unroll
      for (int j = 0; j < 4; j++)
        acc[i][j] = __builtin_amdgcn_mfma_f32_16x16x32_bf16(aF[i], bF[j], acc[i][j], 0, 0, 0);
    __syncthreads();
  }
  // epilogue: C/D layout col=lm (n), row=lg*4+r (m)
#pragma unroll
  for (int i = 0; i < 4; i++)
#pragma unroll
    for (int j = 0; j < 4; j++) {
      const int row = bm + wm + i * 16 + lg * 4;
      const int col = bn + wn + j * 16 + lm;
#pragma unroll
      for (int r = 0; r < 4; r++) {
        if constexpr (CF32) {
          ((float*)Cp)[(size_t)(row + r) * N + col] = acc[i][j][r];
        } else {
          ((unsigned short*)Cp)[(size_t)(row + r) * N + col] = f2bf_hu(acc[i][j][r]);
        }
      }
    }
}

// ---------------------------------------------------------------------------
// SparseNormer attention, one (b, h, 128-q tile) per block, 256 threads.
// S^T = K.Q^T (C-layout regs = 4 consecutive sk at fixed q: mask frag = one
// aligned int4 load, P writes = packed b64), then O^T = V^T.P^T.
// Pipeline: K/V for tile kt+1 prefetched into registers during tile kt's
// compute; mask preloaded before the S-MFMAs. Numerator/denominator
// accumulate across 32 K-tiles; one divide at the end (ratio of sums).
// ---------------------------------------------------------------------------
__global__ __launch_bounds__(256)
void attn_sn(const unsigned short* __restrict__ Qb,
             const unsigned short* __restrict__ Kb,
             const unsigned short* __restrict__ Vb,
             const int* __restrict__ mask,
             const float* __restrict__ snb,
             unsigned short* __restrict__ Ob) {
  __shared__ unsigned short Ks[64 * 72];    // [key][d], pad 64->72
  __shared__ unsigned short Vt[64 * 72];    // [d][sk] transposed, pad->72
  __shared__ unsigned short Pq[128 * 72];   // [q][sk] bf16 P; reused as [q][d] O-stage
  __shared__ float denomS[128];

  const int h = blockIdx.x, qt = blockIdx.y, b = blockIdx.z;
  const int t = threadIdx.x, w = t >> 6, l = t & 63;
  const int lm = l & 15, lg = l >> 4;
  const int q0 = qt * 128;
  const int wk = (w >> 1) * 32;   // wave's sk rows (S^T) == d rows (PV)
  const int wn = (w & 1) * 64;    // wave's q cols (both phases)
  const float bias = snb[0];

  // resident Q fragments: B-operand of S^T (n=q, k=d)
  bf16x8 bQ[4][2];
#pragma unroll
  for (int ni = 0; ni < 4; ni++)
#pragma unroll
    for (int kf = 0; kf < 2; kf++) {
      const int qq = q0 + wn + ni * 16 + lm;
      bQ[ni][kf] = *(const bf16x8*)&Qb[(size_t)(b * NQ_ + qq) * HS_ + h * D_ + kf * 32 + lg * 8];
    }

  // K staging coords: thread t loads rows (t>>3, t>>3+32), cols (t&7)*8..+7
  const int kr = t >> 3, kc = (t & 7) * 8;
  const unsigned short* Kg = Kb + (size_t)(b * SK_) * HS_ + h * D_ + kc;
  // V transpose coords: rows 2*va, 2*va+1, cols vc..vc+7
  const int va = t & 31;
  const int vc = (t >> 5) * 8;
  const unsigned short* Vg = Vb + (size_t)(b * SK_) * HS_ + h * D_ + vc;
  const int* mbase = mask + (size_t)b * NQ_ * SK_;

  f32x4 oacc[2][4] = {};
  float dpart[4] = {0.f, 0.f, 0.f, 0.f};

  // prefetch K/V tile 0 into registers
  u16x8 pk0 = *(const u16x8*)(Kg + (size_t)(kr) * HS_);
  u16x8 pk1 = *(const u16x8*)(Kg + (size_t)(32 + kr) * HS_);
  u16x8 pv0 = *(const u16x8*)(Vg + (size_t)(2 * va) * HS_);
  u16x8 pv1 = *(const u16x8*)(Vg + (size_t)(2 * va + 1) * HS_);

  for (int kt = 0; kt < SK_ / 64; kt++) {
    const int kk0 = kt * 64;
    // --- stage prefetched K tile
    *(u16x8*)&Ks[kr * 72 + kc]        = pk0;
    *(u16x8*)&Ks[(kr + 32) * 72 + kc] = pk1;
    // --- stage prefetched V transposed: v_perm pairs (8 perms, 16 b32 writes)
    {
      union { u16x8 s; unsigned int w4[4]; } a0, a1;
      a0.s = pv0; a1.s = pv1;
#pragma unroll
      for (int ww = 0; ww < 4; ww++) {
        unsigned int lo = __builtin_amdgcn_perm(a1.w4[ww], a0.w4[ww], 0x05040100u);
        unsigned int hi = __builtin_amdgcn_perm(a1.w4[ww], a0.w4[ww], 0x07060302u);
        *(unsigned int*)&Vt[(vc + 2 * ww) * 72 + 2 * va]     = lo;
        *(unsigned int*)&Vt[(vc + 2 * ww + 1) * 72 + 2 * va] = hi;
      }
    }
    __syncthreads();

    // --- issue next-tile K/V global loads (latency hidden behind this tile)
    if (kt + 1 < SK_ / 64) {
      const int nk0 = kk0 + 64;
      pk0 = *(const u16x8*)(Kg + (size_t)(nk0 + kr) * HS_);
      pk1 = *(const u16x8*)(Kg + (size_t)(nk0 + 32 + kr) * HS_);
      pv0 = *(const u16x8*)(Vg + (size_t)(nk0 + 2 * va) * HS_);
      pv1 = *(const u16x8*)(Vg + (size_t)(nk0 + 2 * va + 1) * HS_);
    }
    // --- preload mask for this tile (consumed after S-MFMAs)
    i32x4 mq[4][2];
#pragma unroll
    for (int ni = 0; ni < 4; ni++) {
      const int* mrow = mbase + (size_t)(q0 + wn + ni * 16 + lm) * SK_ + kk0 + wk + lg * 4;
#pragma unroll
      for (int mi = 0; mi < 2; mi++) mq[ni][mi] = *(const i32x4*)(mrow + mi * 16);
    }

    // --- S^T = K . Q^T  (A = K rows)
    bf16x8 aK[2][2];
#pragma unroll
    for (int mi = 0; mi < 2; mi++)
#pragma unroll
      for (int kf = 0; kf < 2; kf++)
        aK[mi][kf] = *(const bf16x8*)&Ks[(wk + mi * 16 + lm) * 72 + kf * 32 + lg * 8];
    f32x4 sf[2][4] = {};
#pragma unroll
    for (int mi = 0; mi < 2; mi++)
#pragma unroll
      for (int ni = 0; ni < 4; ni++) {
        sf[mi][ni] = __builtin_amdgcn_mfma_f32_16x16x32_bf16(aK[mi][0], bQ[ni][0], sf[mi][ni], 0, 0, 0);
        sf[mi][ni] = __builtin_amdgcn_mfma_f32_16x16x32_bf16(aK[mi][1], bQ[ni][1], sf[mi][ni], 0, 0, 0);
      }

    // --- mask + relu^2 (~7.5 VALU/elem), denom on pre-rounded x^2 (denominator
    //     rounding averages out: ~6e-5 relative), pack P via v_perm -> b64
#pragma unroll
    for (int ni = 0; ni < 4; ni++) {
      float dsum = 0.f;
#pragma unroll
      for (int mi = 0; mi < 2; mi++) {
        const i32x4 mw = mq[ni][mi];
        const f32x4 sv = sf[mi][ni];
        float x2[4];
#pragma unroll
        for (int r = 0; r < 4; r++) {
          float x = fmaxf(sv[r] * 0.125f + bias, 0.f);  // scores/sqrt(64)+bias
          x = mw[r] ? 0.f : x;                          // mask True -> 0
          x2[r] = x * x;
          dsum += x2[r];
        }
        const unsigned long long pk =
            (unsigned long long)pack2(x2[0], x2[1]) |
            ((unsigned long long)pack2(x2[2], x2[3]) << 32);
        *(unsigned long long*)&Pq[(wn + ni * 16 + lm) * 72 + wk + mi * 16 + lg * 4] = pk;
      }
      dpart[ni] += dsum;
    }
    __syncthreads();

    // --- O^T += V^T . P^T
#pragma unroll
    for (int k2 = 0; k2 < 2; k2++) {
      bf16x8 aV[2], bP[4];
#pragma unroll
      for (int mi = 0; mi < 2; mi++)
        aV[mi] = *(const bf16x8*)&Vt[(wk + mi * 16 + lm) * 72 + k2 * 32 + lg * 8];
#pragma unroll
      for (int ni = 0; ni < 4; ni++)
        bP[ni] = *(const bf16x8*)&Pq[(wn + ni * 16 + lm) * 72 + k2 * 32 + lg * 8];
#pragma unroll
      for (int mi = 0; mi < 2; mi++)
#pragma unroll
        for (int ni = 0; ni < 4; ni++)
          oacc[mi][ni] = __builtin_amdgcn_mfma_f32_16x16x32_bf16(aV[mi], bP[ni], oacc[mi][ni], 0, 0, 0);
    }
    __syncthreads();
  }

  // --- denominator: reduce 4 lane-groups (shfl) then combine 2 sk-wave-halves
#pragma unroll
  for (int ni = 0; ni < 4; ni++) {
    float v = dpart[ni];
    v += __shfl_xor(v, 16, 64);
    v += __shfl_xor(v, 32, 64);
    dpart[ni] = v;
  }
  if (((w >> 1) == 0) && (lg == 0)) {
#pragma unroll
    for (int ni = 0; ni < 4; ni++) denomS[wn + ni * 16 + lm] = dpart[ni];
  }
  __syncthreads();
  if (((w >> 1) == 1) && (lg == 0)) {
#pragma unroll
    for (int ni = 0; ni < 4; ni++) denomS[wn + ni * 16 + lm] += dpart[ni];
  }
  __syncthreads();

  // --- normalize, stage O[q][d] into Pq (packed b64), then coalesced store
#pragma unroll
  for (int ni = 0; ni < 4; ni++) {
    const int ql = wn + ni * 16 + lm;
    const float inv = 1.0f / (denomS[ql] + 1e-32f);
#pragma unroll
    for (int mi = 0; mi < 2; mi++) {
      const int d0 = wk + mi * 16 + lg * 4;
      const f32x4 ov = oacc[mi][ni];
      const unsigned long long pk =
          (unsigned long long)pack2(ov[0] * inv, ov[1] * inv) |
          ((unsigned long long)pack2(ov[2] * inv, ov[3] * inv) << 32);
      *(unsigned long long*)&Pq[ql * 72 + d0] = pk;
    }
  }
  __syncthreads();
  const int qf = t >> 1;
  const int dg = (t & 1) * 32;
  unsigned short* orow = Ob + (size_t)(b * NQ_ + q0 + qf) * HS_ + h * D_ + dg;
#pragma unroll
  for (int j = 0; j < 4; j++) {
    u16x8 vv = *(const u16x8*)&Pq[qf * 72 + dg + j * 8];
    *(u16x8*)(orow + j * 8) = vv;
  }
}

// ---------------------------------------------------------------------------
extern "C" void kernel_launch(void* const* d_in, const int* in_sizes, int n_in,
                              void* d_out, int out_size, void* d_ws, size_t ws_size,
                              hipStream_t stream) {
  (void)in_sizes; (void)n_in; (void)out_size;
  const float* iQ  = (const float*)d_in[0];
  const float* iK  = (const float*)d_in[1];
  const float* iV  = (const float*)d_in[2];
  const int*   msk = (const int*)d_in[3];   // numpy bool -> int32 per harness
  const float* Wq  = (const float*)d_in[4];
  const float* Wk  = (const float*)d_in[5];
  const float* Wv  = (const float*)d_in[6];
  const float* Wo  = (const float*)d_in[7];
  const float* snb = (const float*)d_in[8];
  float* out = (float*)d_out;

  const size_t TOK = (size_t)B_ * NQ_ * HS_;  // 8.39M elems; bf16 buf = 16.78 MB
  unsigned short *Qb, *Kb, *Vb, *Ob;
  if (ws_size >= 4 * TOK * sizeof(unsigned short)) {
    Qb = (unsigned short*)d_ws;
    Kb = Qb + TOK;
    Vb = Qb + 2 * TOK;
    Ob = Qb + 3 * TOK;
  } else {
    // fallback: stage Q in d_out (fp32 buffer, 33.5 MB >= 16.78 MB; dead
    // until the final GEMM overwrites it after attention completed)
    Qb = (unsigned short*)d_out;
    Kb = (unsigned short*)d_ws;
    Vb = Kb + TOK;
    Ob = Kb + 2 * TOK;
  }

  dim3 gg(64, 8, 1), bb(256, 1, 1);
  const int M = B_ * NQ_, N = HS_, K = HS_;
  hipLaunchKernelGGL((gemm_bt<false, false>), gg, bb, 0, stream, (const void*)iQ, Wq, (void*)Qb, M, N, K);
  hipLaunchKernelGGL((gemm_bt<false, false>), gg, bb, 0, stream, (const void*)iK, Wk, (void*)Kb, M, N, K);
  hipLaunchKernelGGL((gemm_bt<false, false>), gg, bb, 0, stream, (const void*)iV, Wv, (void*)Vb, M, N, K);
  // h fastest-varying: 16 consecutive blocks share one mask tile -> L2 reuse
  hipLaunchKernelGGL(attn_sn, dim3(H_, NQ_ / 128, B_), bb, 0, stream,
                     Qb, Kb, Vb, msk, snb, Ob);
  hipLaunchKernelGGL((gemm_bt<true, true>), gg, bb, 0, stream, (const void*)Ob, Wo, (void*)out, M, N, K);
}

// Round 6
// 485.612 us; speedup vs baseline: 1.1706x; 1.0266x over previous
//
#include <hip/hip_runtime.h>
#include <stdint.h>

// Problem constants
#define B_   4
#define NQ_  2048
#define SK_  2048
#define H_   16
#define HS_  1024   // HSIZE = OSIZE = ISIZE
#define D_   64

typedef __attribute__((ext_vector_type(8))) short bf16x8;          // MFMA A/B frag (4 VGPR)
typedef __attribute__((ext_vector_type(4))) float f32x4;           // MFMA C/D frag
typedef __attribute__((ext_vector_type(8))) unsigned short u16x8;  // 8 bf16 = 16B
typedef __attribute__((ext_vector_type(4))) int i32x4;             // 4 int32 = 16B

#define DEVI __device__ __forceinline__

// fp32 -> bf16, round-half-up (1 v_add)
DEVI unsigned short f2bf_hu(float f) {
  union { float f; unsigned int i; } x; x.f = f;
  return (unsigned short)((x.i + 0x8000u) >> 16);
}
// two fp32 -> packed bf16x2: 2 v_add + 1 v_perm
DEVI unsigned int pack2(float a, float b) {
  union { float f; unsigned int i; } x, y; x.f = a; y.f = b;
  return __builtin_amdgcn_perm(y.i + 0x8000u, x.i + 0x8000u, 0x07060302u);
}
DEVI u16x8 cvt8(f32x4 lo, f32x4 hi) {  // 8 fp32 -> 8 bf16
  union { u16x8 s; unsigned int w[4]; } r;
  r.w[0] = pack2(lo[0], lo[1]);
  r.w[1] = pack2(lo[2], lo[3]);
  r.w[2] = pack2(hi[0], hi[1]);
  r.w[3] = pack2(hi[2], hi[3]);
  return r.s;
}
DEVI void async16(void* lds, const void* g) {  // 16B global->LDS DMA (dest = lane-contiguous)
  __builtin_amdgcn_global_load_lds(
      (const __attribute__((address_space(1))) unsigned int*)g,
      (__attribute__((address_space(3))) unsigned int*)lds, 16, 0, 0);
}

// ---------------------------------------------------------------------------
// Prep: fp32 -> bf16 for one activation tensor (naBlocks*2048 elems) and one
// weight tensor (rest of grid). Memory-bound.
// ---------------------------------------------------------------------------
__global__ __launch_bounds__(256)
void cvt_prep(const float* __restrict__ a, unsigned short* __restrict__ ab,
              const float* __restrict__ wsrc, unsigned short* __restrict__ wdst,
              int naBlocks) {
  const int bi = blockIdx.x;
  const float* s; unsigned short* d; size_t base;
  if (bi < naBlocks) { s = a;    d = ab;   base = (size_t)bi * 2048; }
  else               { s = wsrc; d = wdst; base = (size_t)(bi - naBlocks) * 2048; }
  const size_t o = base + (size_t)threadIdx.x * 8;
  f32x4 lo = *(const f32x4*)(s + o);
  f32x4 hi = *(const f32x4*)(s + o + 4);
  *(u16x8*)(d + o) = cvt8(lo, hi);
}

// mask int32 -> bitmask (bit i of word w = mask[w*64+i]); 67 MB -> 2 MB
__global__ __launch_bounds__(256)
void pack_mask(const int* __restrict__ m, unsigned long long* __restrict__ bits) {
  const size_t tid = (size_t)blockIdx.x * 256 + threadIdx.x;
  const unsigned long long bal = __ballot(m[tid] != 0);
  if ((threadIdx.x & 63) == 0) bits[tid >> 6] = bal;
}

// ---------------------------------------------------------------------------
// FAST GEMM: C[M][N] = A[M][K] @ W[N][K]^T, A/W bf16 via global_load_lds(16B).
// 128x128 tile, BK=32, 4 waves. XOR swizzle (colgrp ^ ((row>>1)&3)) applied on
// the GLOBAL side so LDS dest stays lane-contiguous for the DMA while frag
// ds_read_b128 lands exactly 2-way per bank (free, m136).
// ---------------------------------------------------------------------------
template <bool CF32>
__global__ __launch_bounds__(256)
void gemm_bb(const unsigned short* __restrict__ A, const unsigned short* __restrict__ Wb,
             void* __restrict__ Cp, int M, int N, int K) {
  __shared__ unsigned short As[128 * 32];
  __shared__ unsigned short Bs[128 * 32];
  const int t = threadIdx.x;
  const int w = t >> 6, l = t & 63;
  const int lm = l & 15, lg = l >> 4;
  const int bm = blockIdx.x * 128, bn = blockIdx.y * 128;
  const int wm = (w >> 1) * 64, wn = (w & 1) * 64;

  const int sr = t >> 2;                            // staged row 0..63 (and +64)
  const int sg = ((t & 3) ^ ((t >> 3) & 3)) * 8;    // swizzled global col-group
  const unsigned short* Ag0 = A + (size_t)(bm + sr) * K + sg;
  const unsigned short* Ag1 = A + (size_t)(bm + sr + 64) * K + sg;
  const unsigned short* Wg0 = Wb + (size_t)(bn + sr) * K + sg;
  const unsigned short* Wg1 = Wb + (size_t)(bn + sr + 64) * K + sg;
  unsigned short* lA0 = &As[t * 8];
  unsigned short* lA1 = &As[t * 8 + 2048];
  unsigned short* lB0 = &Bs[t * 8];
  unsigned short* lB1 = &Bs[t * 8 + 2048];

  const int fx = (lm >> 1) & 3;  // frag-read swizzle: (row>>1)&3 == (lm>>1)&3
  f32x4 acc[4][4] = {};

  for (int k0 = 0; k0 < K; k0 += 32) {
    async16(lA0, Ag0 + k0);
    async16(lA1, Ag1 + k0);
    async16(lB0, Wg0 + k0);
    async16(lB1, Wg1 + k0);
    __syncthreads();
    bf16x8 aF[4], bF[4];
#pragma unroll
    for (int i = 0; i < 4; i++)
      aF[i] = *(const bf16x8*)&As[(wm + i * 16 + lm) * 32 + ((lg ^ fx) * 8)];
#pragma unroll
    for (int i = 0; i < 4; i++)
      bF[i] = *(const bf16x8*)&Bs[(wn + i * 16 + lm) * 32 + ((lg ^ fx) * 8)];
#pragma unroll
    for (int i = 0; i < 4; i++)
#pragma unroll
      for (int j = 0; j < 4; j++)
        acc[i][j] = __builtin_amdgcn_mfma_f32_16x16x32_bf16(aF[i], bF[j], acc[i][j], 0, 0, 0);
    __syncthreads();
  }
#pragma unroll
  for (int i = 0; i < 4; i++)
#pragma unroll
    for (int j = 0; j < 4; j++) {
      const int row = bm + wm + i * 16 + lg * 4;
      const int col = bn + wn + j * 16 + lm;
#pragma unroll
      for (int r = 0; r < 4; r++) {
        if constexpr (CF32) {
          ((float*)Cp)[(size_t)(row + r) * N + col] = acc[i][j][r];
        } else {
          ((unsigned short*)Cp)[(size_t)(row + r) * N + col] = f2bf_hu(acc[i][j][r]);
        }
      }
    }
}

// ---------------------------------------------------------------------------
// FALLBACK GEMM (round-5): fp32 inputs, cvt-on-stage, register prefetch.
// ---------------------------------------------------------------------------
template <bool ABF16, bool CF32>
__global__ __launch_bounds__(256)
void gemm_bt(const void* __restrict__ Ap, const float* __restrict__ W,
             void* __restrict__ Cp, int M, int N, int K) {
  __shared__ unsigned short As[128 * 40];
  __shared__ unsigned short Bs[128 * 40];
  const int t = threadIdx.x;
  const int w = t >> 6, l = t & 63;
  const int lm = l & 15, lg = l >> 4;
  const int bm = blockIdx.x * 128, bn = blockIdx.y * 128;
  const int wm = (w >> 1) * 64, wn = (w & 1) * 64;
  const int sr = t >> 2, sc = (t & 3) * 8;
  const float* Af = (const float*)Ap;
  const unsigned short* Ab = (const unsigned short*)Ap;
  const size_t ao0 = (size_t)(bm + sr) * K + sc;
  const size_t ao1 = (size_t)(bm + sr + 64) * K + sc;
  const size_t wo0 = (size_t)(bn + sr) * K + sc;
  const size_t wo1 = (size_t)(bn + sr + 64) * K + sc;
  auto loadA = [&](size_t off) -> u16x8 {
    if constexpr (ABF16) {
      return *(const u16x8*)(Ab + off);
    } else {
      f32x4 lo = *(const f32x4*)(Af + off);
      f32x4 hi = *(const f32x4*)(Af + off + 4);
      return cvt8(lo, hi);
    }
  };
  auto loadW = [&](size_t off) -> u16x8 {
    f32x4 lo = *(const f32x4*)(W + off);
    f32x4 hi = *(const f32x4*)(W + off + 4);
    return cvt8(lo, hi);
  };
  u16x8 pa0 = loadA(ao0), pa1 = loadA(ao1);
  u16x8 pb0 = loadW(wo0), pb1 = loadW(wo1);
  f32x4 acc[4][4] = {};
  for (int k0 = 0; k0 < K; k0 += 32) {
    *(u16x8*)&As[sr * 40 + sc]        = pa0;
    *(u16x8*)&As[(sr + 64) * 40 + sc] = pa1;
    *(u16x8*)&Bs[sr * 40 + sc]        = pb0;
    *(u16x8*)&Bs[(sr + 64) * 40 + sc] = pb1;
    __syncthreads();
    if (k0 + 32 < K) {
      pa0 = loadA(ao0 + k0 + 32);
      pa1 = loadA(ao1 + k0 + 32);
      pb0 = loadW(wo0 + k0 + 32);
      pb1 = loadW(wo1 + k0 + 32);
    }
    bf16x8 aF[4], bF[4];
#pragma unroll
    for (int i = 0; i < 4; i++)
      aF[i] = *(const bf16x8*)&As[(wm + i * 16 + lm) * 40 + lg * 8];
#pragma unroll
    for (int i = 0; i < 4; i++)
      bF[i] = *(const bf16x8*)&Bs[(wn + i * 16 + lm) * 40 + lg * 8];
#pragma unroll
    for (int i = 0; i < 4; i++)
#pragma unroll
      for (int j = 0; j < 4; j++)
        acc[i][j] = __builtin_amdgcn_mfma_f32_16x16x32_bf16(aF[i], bF[j], acc[i][j], 0, 0, 0);
    __syncthreads();
  }
#pragma unroll
  for (int i = 0; i < 4; i++)
#pragma unroll
    for (int j = 0; j < 4; j++) {
      const int row = bm + wm + i * 16 + lg * 4;
      const int col = bn + wn + j * 16 + lm;
#pragma unroll
      for (int r = 0; r < 4; r++) {
        if constexpr (CF32) {
          ((float*)Cp)[(size_t)(row + r) * N + col] = acc[i][j][r];
        } else {
          ((unsigned short*)Cp)[(size_t)(row + r) * N + col] = f2bf_hu(acc[i][j][r]);
        }
      }
    }
}

// ---------------------------------------------------------------------------
// SparseNormer attention, one (b, h, 128-q tile) per block, 256 threads.
// BITMASK=true: mask from 2 MB bit-pack (1 u32/lane/ni/tile); else int32.
// ---------------------------------------------------------------------------
template <bool BITMASK>
__global__ __launch_bounds__(256)
void attn_sn(const unsigned short* __restrict__ Qb,
             const unsigned short* __restrict__ Kb,
             const unsigned short* __restrict__ Vb,
             const int* __restrict__ mask,
             const unsigned int* __restrict__ bits,
             const float* __restrict__ snb,
             unsigned short* __restrict__ Ob) {
  __shared__ unsigned short Ks[64 * 72];
  __shared__ unsigned short Vt[64 * 72];
  __shared__ unsigned short Pq[128 * 72];
  __shared__ float denomS[128];

  const int h = blockIdx.x, qt = blockIdx.y, b = blockIdx.z;
  const int t = threadIdx.x, w = t >> 6, l = t & 63;
  const int lm = l & 15, lg = l >> 4;
  const int q0 = qt * 128;
  const int wk = (w >> 1) * 32;
  const int wn = (w & 1) * 64;
  const float bias = snb[0];

  bf16x8 bQ[4][2];
#pragma unroll
  for (int ni = 0; ni < 4; ni++)
#pragma unroll
    for (int kf = 0; kf < 2; kf++) {
      const int qq = q0 + wn + ni * 16 + lm;
      bQ[ni][kf] = *(const bf16x8*)&Qb[(size_t)(b * NQ_ + qq) * HS_ + h * D_ + kf * 32 + lg * 8];
    }

  const int kr = t >> 3, kc = (t & 7) * 8;
  const unsigned short* Kg = Kb + (size_t)(b * SK_) * HS_ + h * D_ + kc;
  const int va = t & 31;
  const int vc = (t >> 5) * 8;
  const unsigned short* Vg = Vb + (size_t)(b * SK_) * HS_ + h * D_ + vc;
  const int* mbase = mask + (size_t)b * NQ_ * SK_;

  f32x4 oacc[2][4] = {};
  float dpart[4] = {0.f, 0.f, 0.f, 0.f};

  u16x8 pk0 = *(const u16x8*)(Kg + (size_t)(kr) * HS_);
  u16x8 pk1 = *(const u16x8*)(Kg + (size_t)(32 + kr) * HS_);
  u16x8 pv0 = *(const u16x8*)(Vg + (size_t)(2 * va) * HS_);
  u16x8 pv1 = *(const u16x8*)(Vg + (size_t)(2 * va + 1) * HS_);

  for (int kt = 0; kt < SK_ / 64; kt++) {
    const int kk0 = kt * 64;
    *(u16x8*)&Ks[kr * 72 + kc]        = pk0;
    *(u16x8*)&Ks[(kr + 32) * 72 + kc] = pk1;
    {
      union { u16x8 s; unsigned int w4[4]; } a0, a1;
      a0.s = pv0; a1.s = pv1;
#pragma unroll
      for (int ww = 0; ww < 4; ww++) {
        unsigned int lo = __builtin_amdgcn_perm(a1.w4[ww], a0.w4[ww], 0x05040100u);
        unsigned int hi = __builtin_amdgcn_perm(a1.w4[ww], a0.w4[ww], 0x07060302u);
        *(unsigned int*)&Vt[(vc + 2 * ww) * 72 + 2 * va]     = lo;
        *(unsigned int*)&Vt[(vc + 2 * ww + 1) * 72 + 2 * va] = hi;
      }
    }
    __syncthreads();

    if (kt + 1 < SK_ / 64) {
      const int nk0 = kk0 + 64;
      pk0 = *(const u16x8*)(Kg + (size_t)(nk0 + kr) * HS_);
      pk1 = *(const u16x8*)(Kg + (size_t)(nk0 + 32 + kr) * HS_);
      pv0 = *(const u16x8*)(Vg + (size_t)(nk0 + 2 * va) * HS_);
      pv1 = *(const u16x8*)(Vg + (size_t)(nk0 + 2 * va + 1) * HS_);
    }
    // --- mask preload
    i32x4 mq[4][2];
    unsigned int mb[4];
    if constexpr (BITMASK) {
#pragma unroll
      for (int ni = 0; ni < 4; ni++)
        mb[ni] = bits[(size_t)(b * NQ_ + q0 + wn + ni * 16 + lm) * 64 + kt * 2 + (wk >> 5)];
    } else {
#pragma unroll
      for (int ni = 0; ni < 4; ni++) {
        const int* mrow = mbase + (size_t)(q0 + wn + ni * 16 + lm) * SK_ + kk0 + wk + lg * 4;
#pragma unroll
        for (int mi = 0; mi < 2; mi++) mq[ni][mi] = *(const i32x4*)(mrow + mi * 16);
      }
    }

    // --- S^T = K . Q^T
    bf16x8 aK[2][2];
#pragma unroll
    for (int mi = 0; mi < 2; mi++)
#pragma unroll
      for (int kf = 0; kf < 2; kf++)
        aK[mi][kf] = *(const bf16x8*)&Ks[(wk + mi * 16 + lm) * 72 + kf * 32 + lg * 8];
    f32x4 sf[2][4] = {};
#pragma unroll
    for (int mi = 0; mi < 2; mi++)
#pragma unroll
      for (int ni = 0; ni < 4; ni++) {
        sf[mi][ni] = __builtin_amdgcn_mfma_f32_16x16x32_bf16(aK[mi][0], bQ[ni][0], sf[mi][ni], 0, 0, 0);
        sf[mi][ni] = __builtin_amdgcn_mfma_f32_16x16x32_bf16(aK[mi][1], bQ[ni][1], sf[mi][ni], 0, 0, 0);
      }

    // --- mask + relu^2, denom, pack P
#pragma unroll
    for (int ni = 0; ni < 4; ni++) {
      float dsum = 0.f;
#pragma unroll
      for (int mi = 0; mi < 2; mi++) {
        const f32x4 sv = sf[mi][ni];
        float x2[4];
#pragma unroll
        for (int r = 0; r < 4; r++) {
          float x = fmaxf(sv[r] * 0.125f + bias, 0.f);
          if constexpr (BITMASK) {
            x = ((mb[ni] >> (mi * 16 + lg * 4 + r)) & 1u) ? 0.f : x;
          } else {
            x = mq[ni][mi][r] ? 0.f : x;
          }
          x2[r] = x * x;
          dsum += x2[r];
        }
        const unsigned long long pk =
            (unsigned long long)pack2(x2[0], x2[1]) |
            ((unsigned long long)pack2(x2[2], x2[3]) << 32);
        *(unsigned long long*)&Pq[(wn + ni * 16 + lm) * 72 + wk + mi * 16 + lg * 4] = pk;
      }
      dpart[ni] += dsum;
    }
    __syncthreads();

    // --- O^T += V^T . P^T
#pragma unroll
    for (int k2 = 0; k2 < 2; k2++) {
      bf16x8 aV[2], bP[4];
#pragma unroll
      for (int mi = 0; mi < 2; mi++)
        aV[mi] = *(const bf16x8*)&Vt[(wk + mi * 16 + lm) * 72 + k2 * 32 + lg * 8];
#pragma unroll
      for (int ni = 0; ni < 4; ni++)
        bP[ni] = *(const bf16x8*)&Pq[(wn + ni * 16 + lm) * 72 + k2 * 32 + lg * 8];
#pragma unroll
      for (int mi = 0; mi < 2; mi++)
#pragma unroll
        for (int ni = 0; ni < 4; ni++)
          oacc[mi][ni] = __builtin_amdgcn_mfma_f32_16x16x32_bf16(aV[mi], bP[ni], oacc[mi][ni], 0, 0, 0);
    }
    __syncthreads();
  }

#pragma unroll
  for (int ni = 0; ni < 4; ni++) {
    float v = dpart[ni];
    v += __shfl_xor(v, 16, 64);
    v += __shfl_xor(v, 32, 64);
    dpart[ni] = v;
  }
  if (((w >> 1) == 0) && (lg == 0)) {
#pragma unroll
    for (int ni = 0; ni < 4; ni++) denomS[wn + ni * 16 + lm] = dpart[ni];
  }
  __syncthreads();
  if (((w >> 1) == 1) && (lg == 0)) {
#pragma unroll
    for (int ni = 0; ni < 4; ni++) denomS[wn + ni * 16 + lm] += dpart[ni];
  }
  __syncthreads();

#pragma unroll
  for (int ni = 0; ni < 4; ni++) {
    const int ql = wn + ni * 16 + lm;
    const float inv = 1.0f / (denomS[ql] + 1e-32f);
#pragma unroll
    for (int mi = 0; mi < 2; mi++) {
      const int d0 = wk + mi * 16 + lg * 4;
      const f32x4 ov = oacc[mi][ni];
      const unsigned long long pk =
          (unsigned long long)pack2(ov[0] * inv, ov[1] * inv) |
          ((unsigned long long)pack2(ov[2] * inv, ov[3] * inv) << 32);
      *(unsigned long long*)&Pq[ql * 72 + d0] = pk;
    }
  }
  __syncthreads();
  const int qf = t >> 1;
  const int dg = (t & 1) * 32;
  unsigned short* orow = Ob + (size_t)(b * NQ_ + q0 + qf) * HS_ + h * D_ + dg;
#pragma unroll
  for (int j = 0; j < 4; j++) {
    u16x8 vv = *(const u16x8*)&Pq[qf * 72 + dg + j * 8];
    *(u16x8*)(orow + j * 8) = vv;
  }
}

// ---------------------------------------------------------------------------
extern "C" void kernel_launch(void* const* d_in, const int* in_sizes, int n_in,
                              void* d_out, int out_size, void* d_ws, size_t ws_size,
                              hipStream_t stream) {
  (void)in_sizes; (void)n_in; (void)out_size;
  const float* iQ  = (const float*)d_in[0];
  const float* iK  = (const float*)d_in[1];
  const float* iV  = (const float*)d_in[2];
  const int*   msk = (const int*)d_in[3];
  const float* Wq  = (const float*)d_in[4];
  const float* Wk  = (const float*)d_in[5];
  const float* Wv  = (const float*)d_in[6];
  const float* Wo  = (const float*)d_in[7];
  const float* snb = (const float*)d_in[8];
  float* out = (float*)d_out;

  const size_t TOK = (size_t)B_ * NQ_ * HS_;           // 8.39M elems
  const size_t WE  = (size_t)HS_ * HS_;                // 1.05M elems
  const size_t BITS_B = (size_t)B_ * NQ_ * SK_ / 8;    // 2.10 MB
  const size_t NEED = (3 * TOK + WE) * 2 + BITS_B;     // 54.5 MB

  const dim3 gg(64, 8, 1), bb(256, 1, 1);
  const dim3 ga(H_, NQ_ / 128, B_);
  const int M = B_ * NQ_, N = HS_, K = HS_;

  if (ws_size >= NEED) {
    // --- fast path: bf16 pre-cvt + global_load_lds GEMM + bitmask attn
    unsigned short* Kb = (unsigned short*)d_ws;
    unsigned short* Vb = Kb + TOK;
    unsigned short* Ob = Vb + TOK;
    unsigned short* Wb = Ob + TOK;
    unsigned int* bits = (unsigned int*)(Wb + WE);
    unsigned short* out_us = (unsigned short*)d_out;
    unsigned short* Qb  = out_us;         // d_out lower half (dead before final GEMM)
    unsigned short* INb = out_us + TOK;   // d_out upper half: staging for bf16 A

    hipLaunchKernelGGL(cvt_prep, dim3(4608), bb, 0, stream, iQ, INb, Wq, Wb, 4096);
    hipLaunchKernelGGL((gemm_bb<false>), gg, bb, 0, stream, INb, Wb, (void*)Qb, M, N, K);
    hipLaunchKernelGGL(cvt_prep, dim3(4608), bb, 0, stream, iK, INb, Wk, Wb, 4096);
    hipLaunchKernelGGL((gemm_bb<false>), gg, bb, 0, stream, INb, Wb, (void*)Kb, M, N, K);
    hipLaunchKernelGGL(cvt_prep, dim3(4608), bb, 0, stream, iV, INb, Wv, Wb, 4096);
    hipLaunchKernelGGL((gemm_bb<false>), gg, bb, 0, stream, INb, Wb, (void*)Vb, M, N, K);
    hipLaunchKernelGGL(cvt_prep, dim3(512), bb, 0, stream,
                       (const float*)nullptr, (unsigned short*)nullptr, Wo, Wb, 0);
    hipLaunchKernelGGL(pack_mask, dim3(65536), bb, 0, stream,
                       msk, (unsigned long long*)bits);
    hipLaunchKernelGGL((attn_sn<true>), ga, bb, 0, stream,
                       Qb, Kb, Vb, msk, bits, snb, Ob);
    hipLaunchKernelGGL((gemm_bb<true>), gg, bb, 0, stream, Ob, Wb, (void*)out, M, N, K);
  } else {
    // --- fallback: round-5 known-good path (needs only 50.3 MB ws)
    unsigned short *Qb, *Kb, *Vb, *Ob;
    if (ws_size >= 4 * TOK * sizeof(unsigned short)) {
      Qb = (unsigned short*)d_ws;
      Kb = Qb + TOK;
      Vb = Qb + 2 * TOK;
      Ob = Qb + 3 * TOK;
    } else {
      Qb = (unsigned short*)d_out;
      Kb = (unsigned short*)d_ws;
      Vb = Kb + TOK;
      Ob = Kb + 2 * TOK;
    }
    hipLaunchKernelGGL((gemm_bt<false, false>), gg, bb, 0, stream, (const void*)iQ, Wq, (void*)Qb, M, N, K);
    hipLaunchKernelGGL((gemm_bt<false, false>), gg, bb, 0, stream, (const void*)iK, Wk, (void*)Kb, M, N, K);
    hipLaunchKernelGGL((gemm_bt<false, false>), gg, bb, 0, stream, (const void*)iV, Wv, (void*)Vb, M, N, K);
    hipLaunchKernelGGL((attn_sn<false>), ga, bb, 0, stream,
                       Qb, Kb, Vb, msk, (const unsigned int*)nullptr, snb, Ob);
    hipLaunchKernelGGL((gemm_bt<true, true>), gg, bb, 0, stream, (const void*)Ob, Wo, (void*)out, M, N, K);
  }
}